// Round 9
// baseline (205.522 us; speedup 1.0000x reference)
//
#include <hip/hip_runtime.h>
#include <math.h>

// PhiCell hysteresis scan: s' = max(x-0.5, min(x+0.5, s)); output o_t = s_t.
// Associative scan over (lo,hi) clamp operators.
// R9: SINGLE-PASS decoupled lookback with atomic ticket (deadlock-free with
// zero co-residency/dispatch-order assumptions: predecessors by ticket order
// are guaranteed running-or-done and publish their aggregate before waiting).
// Coalesced loads + verified swizzled-LDS transpose (R7). x read exactly once.

#define T_ELEMS 8388608
#define NEG_INF (-__builtin_inff())
#define POS_INF (__builtin_inff())

#define BLOCK   256
#define WAVES   4
#define F4T     8                         // float4 per thread (32 floats)
#define F4W     (64 * F4T)                // 512 float4 per wave region
#define F4B     (BLOCK * F4T)             // 2048 float4 per block
#define EPB     (F4B * 4)                 // 8192 floats per block
#define NBLK    (T_ELEMS / EPB)           // 1024 tiles

struct Op { float lo, hi; };

// Apply operator a first, then b:  result(s) = b(a(s))
__device__ __forceinline__ Op combine(Op a, Op b) {
    Op r;
    r.lo = fmaxf(b.lo, fminf(b.hi, a.lo));
    r.hi = fminf(b.hi, a.hi);
    return r;
}
__device__ __forceinline__ float apply_op(Op o, float s) {
    return fmaxf(o.lo, fminf(o.hi, s));
}
__device__ __forceinline__ void fold_elem(Op& t, float e) {
    float elo = e - 0.5f, ehi = e + 0.5f;
    t.lo = fmaxf(elo, fminf(ehi, t.lo));
    t.hi = fminf(ehi, t.hi);
}
__device__ __forceinline__ void fold4(Op& t, float4 v) {
    fold_elem(t, v.x); fold_elem(t, v.y); fold_elem(t, v.z); fold_elem(t, v.w);
}
// XOR swizzle on float4 index within a 512-float4 wave region (verified R5/R7).
__device__ __forceinline__ int swz(int idx) { return idx ^ ((idx >> 3) & 7); }

__device__ __forceinline__ unsigned long long pack(Op o) {
    float2 f = make_float2(o.lo, o.hi);
    return __builtin_bit_cast(unsigned long long, f);
}
__device__ __forceinline__ Op unpack(unsigned long long p) {
    float2 f = __builtin_bit_cast(float2, p);
    Op o = { f.x, f.y };
    return o;
}

// Ordered wave-inclusive scan (lane order = time order).
__device__ __forceinline__ Op wave_incl_scan(Op t, int lane) {
#pragma unroll
    for (int off = 1; off < 64; off <<= 1) {
        float nlo = __shfl_up(t.lo, off);
        float nhi = __shfl_up(t.hi, off);
        if (lane >= off) {
            Op prev = { nlo, nhi };
            t = combine(prev, t);
        }
    }
    return t;
}
// Ordered wave reduction (result valid in lane 0; folds lane 0..63 in order).
__device__ __forceinline__ Op wave_reduce(Op t) {
#pragma unroll
    for (int off = 1; off < 64; off <<= 1) {
        Op nb;
        nb.lo = __shfl_down(t.lo, off);
        nb.hi = __shfl_down(t.hi, off);
        t = combine(t, nb);
    }
    return t;
}

// ---------------- init: zero ticket + flags (d_ws is 0xAA-poisoned) --------
__global__ void init_ws(unsigned int* ws) {
    int i = blockIdx.x * blockDim.x + threadIdx.x;
    if (i < 1 + 2 * NBLK) ws[i] = 0u;     // [0]=ticket, [1..]=aggFlag, incFlag
}

// ---------------- single-pass scan kernel ----------------
__global__ __launch_bounds__(BLOCK) void phik(const float* __restrict__ x,
                                              const float* __restrict__ w,
                                              const float* __restrict__ s0,
                                              float* __restrict__ out,
                                              unsigned int* __restrict__ ticket,
                                              unsigned int* __restrict__ aggFlag,
                                              unsigned int* __restrict__ incFlag,
                                              unsigned long long* __restrict__ aggVal,
                                              unsigned long long* __restrict__ incVal) {
    __shared__ float4 xbuf[WAVES * F4W];   // 32 KB transpose buffer
    __shared__ Op wtA[WAVES];
    __shared__ Op sExcl;
    __shared__ int sVt;

    const int tid = threadIdx.x, lane = tid & 63, wid = tid >> 6;
    const float wv = w[0];

    if (tid == 0)
        sVt = (int)__hip_atomic_fetch_add(ticket, 1u, __ATOMIC_RELAXED,
                                          __HIP_MEMORY_SCOPE_AGENT);
    __syncthreads();
    const int vt = sVt;                    // virtual tile = arrival order

    // ---- load tile vt: coalesced + swizzled-LDS transpose -> v[0..7] ----
    float4* wbuf = xbuf + wid * F4W;
    const size_t wbase = (size_t)vt * F4B + (size_t)wid * F4W;
    const float4* xg = reinterpret_cast<const float4*>(x);

    float4 v[F4T];
#pragma unroll
    for (int j = 0; j < F4T; ++j) {
        float4 t = xg[wbase + j * 64 + lane];
        t.x *= wv; t.y *= wv; t.z *= wv; t.w *= wv;
        wbuf[swz(j * 64 + lane)] = t;
    }
#pragma unroll
    for (int k = 0; k < F4T; ++k)
        v[k] = wbuf[swz(lane * F4T + k)];

    // ---- in-block scan ----
    Op t = { v[0].x - 0.5f, v[0].x + 0.5f };
    fold_elem(t, v[0].y); fold_elem(t, v[0].z); fold_elem(t, v[0].w);
#pragma unroll
    for (int k = 1; k < F4T; ++k) fold4(t, v[k]);

    Op incl = wave_incl_scan(t, lane);
    if (lane == 63) wtA[wid] = incl;
    __syncthreads();

    // ---- wave 0: publish aggregate, decoupled lookback, publish prefix ----
    if (wid == 0) {
        Op blockAgg = combine(combine(combine(wtA[0], wtA[1]), wtA[2]), wtA[3]);
        if (lane == 0) {
            __hip_atomic_store(&aggVal[vt], pack(blockAgg), __ATOMIC_RELAXED,
                               __HIP_MEMORY_SCOPE_AGENT);
            __hip_atomic_store(&aggFlag[vt], 1u, __ATOMIC_RELEASE,
                               __HIP_MEMORY_SCOPE_AGENT);
        }

        Op run = { NEG_INF, POS_INF };     // folds tiles (idx+1 .. vt-1)
        bool done = (vt == 0);
        int idx = vt - 1;
        while (!done) {
            const int wb = idx - 63;       // window base (may be < 0)
            const int wtile = wb + lane;   // this lane's tile
            Op val = { NEG_INF, POS_INF };
            int f = 0;
            if (wtile >= 0) {
                while (true) {
                    if (__hip_atomic_load(&incFlag[wtile], __ATOMIC_ACQUIRE,
                                          __HIP_MEMORY_SCOPE_AGENT)) {
                        val = unpack(__hip_atomic_load(&incVal[wtile], __ATOMIC_RELAXED,
                                                       __HIP_MEMORY_SCOPE_AGENT));
                        f = 2;
                        break;
                    }
                    if (__hip_atomic_load(&aggFlag[wtile], __ATOMIC_ACQUIRE,
                                          __HIP_MEMORY_SCOPE_AGENT)) {
                        val = unpack(__hip_atomic_load(&aggVal[wtile], __ATOMIC_RELAXED,
                                                       __HIP_MEMORY_SCOPE_AGENT));
                        f = 1;
                        break;
                    }
                    __builtin_amdgcn_s_sleep(1);
                }
            }
            const unsigned long long pmask = __ballot(f == 2);
            if (pmask) {
                const int p = 63 - __builtin_clzll(pmask);   // closest P to us
                Op contrib = (lane < p) ? Op{ NEG_INF, POS_INF } : val;
                Op wsum = wave_reduce(contrib);              // = fold(tiles 0..idx)
                run = combine(wsum, run);
                done = true;
            } else {
                Op wsum = wave_reduce(val);                  // fold(wb..idx) aggs
                run = combine(wsum, run);
                if (wb <= 0) done = true;
                else idx = wb - 1;
            }
        }
        if (lane == 0) {
            sExcl = run;                                     // fold(tiles 0..vt-1)
            Op blockAgg2 = combine(combine(combine(wtA[0], wtA[1]), wtA[2]), wtA[3]);
            __hip_atomic_store(&incVal[vt], pack(combine(run, blockAgg2)),
                               __ATOMIC_RELAXED, __HIP_MEMORY_SCOPE_AGENT);
            __hip_atomic_store(&incFlag[vt], 1u, __ATOMIC_RELEASE,
                               __HIP_MEMORY_SCOPE_AGENT);
        }
    }
    __syncthreads();
    const Op Eb = sExcl;

    // ---- thread's in-block exclusive operator ----
    Op wpre = { NEG_INF, POS_INF };
    for (int k = 0; k < wid; ++k) wpre = combine(wpre, wtA[k]);
    float elo = __shfl_up(incl.lo, 1);
    float ehi = __shfl_up(incl.hi, 1);
    Op excl;
    if (lane == 0) { excl.lo = NEG_INF; excl.hi = POS_INF; }
    else           { excl.lo = elo;     excl.hi = ehi;     }

    float s = apply_op(Eb, s0[0]);            // state entering this tile
    s = apply_op(combine(wpre, excl), s);     // state entering this thread

    // ---- apply + coalesced store through the same transpose ----
    float4* og = reinterpret_cast<float4*>(out);
#pragma unroll
    for (int k = 0; k < F4T; ++k) {
        float4 e = v[k], o4;
        s = fmaxf(e.x - 0.5f, fminf(e.x + 0.5f, s)); o4.x = s;
        s = fmaxf(e.y - 0.5f, fminf(e.y + 0.5f, s)); o4.y = s;
        s = fmaxf(e.z - 0.5f, fminf(e.z + 0.5f, s)); o4.z = s;
        s = fmaxf(e.w - 0.5f, fminf(e.w + 0.5f, s)); o4.w = s;
        wbuf[swz(lane * F4T + k)] = o4;
    }
#pragma unroll
    for (int j = 0; j < F4T; ++j)
        og[wbase + j * 64 + lane] = wbuf[swz(j * 64 + lane)];

    if (vt == NBLK - 1 && tid == BLOCK - 1)
        out[T_ELEMS] = s;                     // final state
}

extern "C" void kernel_launch(void* const* d_in, const int* in_sizes, int n_in,
                              void* d_out, int out_size, void* d_ws, size_t ws_size,
                              hipStream_t stream) {
    const float* x  = (const float*)d_in[0];   // (1, T) f32
    const float* w  = (const float*)d_in[1];   // (1, 1) f32
    const float* s0 = (const float*)d_in[2];   // (1, 1) f32
    float* out = (float*)d_out;                // [T outputs | final state]

    // d_ws layout (24 KB + slack):
    unsigned int* ticket  = (unsigned int*)d_ws;                        // [0]
    unsigned int* aggFlag = ticket + 1;                                 // NBLK
    unsigned int* incFlag = aggFlag + NBLK;                             // NBLK
    unsigned long long* aggVal = (unsigned long long*)((char*)d_ws + 16384);
    unsigned long long* incVal = aggVal + NBLK;

    init_ws<<<(1 + 2 * NBLK + 255) / 256, 256, 0, stream>>>(ticket);
    phik<<<NBLK, BLOCK, 0, stream>>>(x, w, s0, out, ticket,
                                     aggFlag, incFlag, aggVal, incVal);
}

// Round 10
// 95.693 us; speedup vs baseline: 2.1477x; 2.1477x over previous
//
#include <hip/hip_runtime.h>
#include <math.h>

// PhiCell hysteresis scan: s' = max(x-0.5, min(x+0.5, s)); output o_t = s_t.
// Associative scan over (lo,hi) clamp operators.
// R10: R7 structure (2 kernels, no inter-block sync — best verified, 92.3us)
// + XCD-aware tile swizzle in BOTH kernels, with K2 walking each XCD's tile
// range in REVERSE so its first reads hit the tiles K1 cached last in that
// XCD's L2 (128 tiles x 32KB = 4MB = one XCD L2). R9 lesson: cross-block
// spin-sync costs >100us on MI355X; kernel boundaries cost ~5us.

#define T_ELEMS 8388608
#define NEG_INF (-__builtin_inff())
#define POS_INF (__builtin_inff())

#define BLOCK   256
#define WAVES   4
#define F4T     8                         // float4 per thread (32 floats)
#define F4W     (64 * F4T)                // 512 float4 per wave region
#define F4B     (BLOCK * F4T)             // 2048 float4 per block
#define EPB     (F4B * 4)                 // 8192 floats per block
#define NBLK    (T_ELEMS / EPB)           // 1024 tiles
#define NXCD    8
#define TPX     (NBLK / NXCD)             // 128 tiles per XCD slice
#define APT     (NBLK / BLOCK)            // 4 agg entries per thread in K2

struct Op { float lo, hi; };

// Apply operator a first, then b:  result(s) = b(a(s))
__device__ __forceinline__ Op combine(Op a, Op b) {
    Op r;
    r.lo = fmaxf(b.lo, fminf(b.hi, a.lo));
    r.hi = fminf(b.hi, a.hi);
    return r;
}
__device__ __forceinline__ float apply_op(Op o, float s) {
    return fmaxf(o.lo, fminf(o.hi, s));
}
__device__ __forceinline__ void fold_elem(Op& t, float e) {
    float elo = e - 0.5f, ehi = e + 0.5f;
    t.lo = fmaxf(elo, fminf(ehi, t.lo));
    t.hi = fminf(ehi, t.hi);
}
__device__ __forceinline__ void fold4(Op& t, float4 v) {
    fold_elem(t, v.x); fold_elem(t, v.y); fold_elem(t, v.z); fold_elem(t, v.w);
}
// XOR swizzle on float4 index within a 512-float4 wave region (verified R5/R7).
__device__ __forceinline__ int swz(int idx) { return idx ^ ((idx >> 3) & 7); }

// Ordered wave-inclusive scan (lane order = time order).
__device__ __forceinline__ Op wave_incl_scan(Op t, int lane) {
#pragma unroll
    for (int off = 1; off < 64; off <<= 1) {
        float nlo = __shfl_up(t.lo, off);
        float nhi = __shfl_up(t.hi, off);
        if (lane >= off) {
            Op prev = { nlo, nhi };
            t = combine(prev, t);
        }
    }
    return t;
}
// Ordered wave reduction (result valid in lane 0).
__device__ __forceinline__ Op wave_reduce(Op t) {
#pragma unroll
    for (int off = 1; off < 64; off <<= 1) {
        Op nb;
        nb.lo = __shfl_down(t.lo, off);
        nb.hi = __shfl_down(t.hi, off);
        t = combine(t, nb);
    }
    return t;
}

// Load a wave's 512-float4 slice of tile `tile`, scale, transpose via swizzled
// LDS so each thread holds 32 time-contiguous floats in v[0..7].
__device__ __forceinline__ void load_tile(const float4* __restrict__ xg,
                                          size_t wbase, int lane, float wv,
                                          float4* wbuf, float4 v[F4T]) {
#pragma unroll
    for (int j = 0; j < F4T; ++j) {
        float4 t = xg[wbase + j * 64 + lane];
        t.x *= wv; t.y *= wv; t.z *= wv; t.w *= wv;
        wbuf[swz(j * 64 + lane)] = t;
    }
#pragma unroll
    for (int k = 0; k < F4T; ++k)
        v[k] = wbuf[swz(lane * F4T + k)];
}

// ---------------- K1: per-block aggregate operators ----------------
// physical block p -> tile (p%8)*128 + p/8 : XCD k owns tiles [k*128, k*128+128)
__global__ __launch_bounds__(BLOCK) void k1_agg(const float* __restrict__ x,
                                                const float* __restrict__ w,
                                                float2* __restrict__ agg) {
    __shared__ float4 xbuf[WAVES * F4W];   // 32 KB
    __shared__ Op wt[WAVES];
    const int tid = threadIdx.x, lane = tid & 63, wid = tid >> 6;
    const int p = blockIdx.x;
    const int tile = (p % NXCD) * TPX + p / NXCD;
    const float wv = w[0];

    float4* wbuf = xbuf + wid * F4W;
    const size_t wbase = (size_t)tile * F4B + (size_t)wid * F4W;
    const float4* xg = reinterpret_cast<const float4*>(x);

    float4 v[F4T];
    load_tile(xg, wbase, lane, wv, wbuf, v);

    Op t = { v[0].x - 0.5f, v[0].x + 0.5f };
    fold_elem(t, v[0].y); fold_elem(t, v[0].z); fold_elem(t, v[0].w);
#pragma unroll
    for (int k = 1; k < F4T; ++k) fold4(t, v[k]);

    t = wave_reduce(t);
    if (lane == 0) wt[wid] = t;
    __syncthreads();
    if (tid == 0) {
        Op bt = wt[0];
#pragma unroll
        for (int k = 1; k < WAVES; ++k) bt = combine(bt, wt[k]);
        agg[tile] = make_float2(bt.lo, bt.hi);
    }
}

// ---------------- K2: per-block prefix fold + apply + store ----------------
// physical block p -> tile (p%8)*128 + (127 - p/8): same XCD slice as K1,
// walked in reverse so first-dispatched blocks hit K1's freshest L2 lines.
__global__ __launch_bounds__(BLOCK) void k2_apply(const float* __restrict__ x,
                                                  const float* __restrict__ w,
                                                  const float* __restrict__ s0,
                                                  const float2* __restrict__ agg,
                                                  float* __restrict__ out) {
    __shared__ float4 xbuf[WAVES * F4W];   // 32 KB
    __shared__ Op wtA[WAVES];              // per-wave inclusive totals (this block)
    __shared__ Op wtP[WAVES];              // prefix-fold partials
    const int tid = threadIdx.x, lane = tid & 63, wid = tid >> 6;
    const int p = blockIdx.x;
    const int tile = (p % NXCD) * TPX + (TPX - 1 - p / NXCD);
    const float wv = w[0];

    // ---- block-exclusive prefix E_b = ordered fold of agg[0..tile-1] ----
    Op seg = { NEG_INF, POS_INF };
#pragma unroll
    for (int j = 0; j < APT; ++j) {
        int i = tid * APT + j;
        if (i < tile) {
            float2 f = agg[i];
            Op o = { f.x, f.y };
            seg = combine(seg, o);
        }
    }
    seg = wave_reduce(seg);
    if (lane == 0) wtP[wid] = seg;

    // ---- load tile, thread ops, in-block scan ----
    float4* wbuf = xbuf + wid * F4W;
    const size_t wbase = (size_t)tile * F4B + (size_t)wid * F4W;
    const float4* xg = reinterpret_cast<const float4*>(x);

    float4 v[F4T];
    load_tile(xg, wbase, lane, wv, wbuf, v);

    Op t = { v[0].x - 0.5f, v[0].x + 0.5f };
    fold_elem(t, v[0].y); fold_elem(t, v[0].z); fold_elem(t, v[0].w);
#pragma unroll
    for (int k = 1; k < F4T; ++k) fold4(t, v[k]);

    Op incl = wave_incl_scan(t, lane);
    if (lane == 63) wtA[wid] = incl;
    __syncthreads();

    Op Eb = wtP[0];
#pragma unroll
    for (int k = 1; k < WAVES; ++k) Eb = combine(Eb, wtP[k]);

    Op wpre = { NEG_INF, POS_INF };
    for (int k = 0; k < wid; ++k) wpre = combine(wpre, wtA[k]);
    float elo = __shfl_up(incl.lo, 1);
    float ehi = __shfl_up(incl.hi, 1);
    Op excl;
    if (lane == 0) { excl.lo = NEG_INF; excl.hi = POS_INF; }
    else           { excl.lo = elo;     excl.hi = ehi;     }

    float s = apply_op(Eb, s0[0]);            // state entering this tile
    s = apply_op(combine(wpre, excl), s);     // state entering this thread

    // ---- apply 32 elems; store through the same transpose ----
    float4* og = reinterpret_cast<float4*>(out);
#pragma unroll
    for (int k = 0; k < F4T; ++k) {
        float4 e = v[k], o4;
        s = fmaxf(e.x - 0.5f, fminf(e.x + 0.5f, s)); o4.x = s;
        s = fmaxf(e.y - 0.5f, fminf(e.y + 0.5f, s)); o4.y = s;
        s = fmaxf(e.z - 0.5f, fminf(e.z + 0.5f, s)); o4.z = s;
        s = fmaxf(e.w - 0.5f, fminf(e.w + 0.5f, s)); o4.w = s;
        wbuf[swz(lane * F4T + k)] = o4;
    }
#pragma unroll
    for (int j = 0; j < F4T; ++j)
        og[wbase + j * 64 + lane] = wbuf[swz(j * 64 + lane)];

    if (tile == NBLK - 1 && tid == BLOCK - 1)
        out[T_ELEMS] = s;                     // final state
}

extern "C" void kernel_launch(void* const* d_in, const int* in_sizes, int n_in,
                              void* d_out, int out_size, void* d_ws, size_t ws_size,
                              hipStream_t stream) {
    const float* x  = (const float*)d_in[0];   // (1, T) f32
    const float* w  = (const float*)d_in[1];   // (1, 1) f32
    const float* s0 = (const float*)d_in[2];   // (1, 1) f32
    float* out = (float*)d_out;                // [T outputs | final state]

    float2* agg = (float2*)d_ws;               // NBLK float2 (8 KB)

    k1_agg<<<NBLK, BLOCK, 0, stream>>>(x, w, agg);
    k2_apply<<<NBLK, BLOCK, 0, stream>>>(x, w, s0, agg, out);
}